// Round 9
// baseline (151.136 us; speedup 1.0000x reference)
//
#include <hip/hip_runtime.h>

#define N_ATOMS 1024
#define N_EDGES 8192
#define EPAD    (N_EDGES + N_ATOMS)
#define NBATCH  256
#define NEG     0.01f

typedef unsigned int u32;
typedef __attribute__((ext_vector_type(2))) float f32x2;
typedef __attribute__((ext_vector_type(4))) float f32x4;
typedef __attribute__((ext_vector_type(8))) _Float16 f16x8;

__device__ __forceinline__ u32 pkrtz(float lo, float hi) {
    u32 r;
    asm("v_cvt_pkrtz_f16_f32 %0, %1, %2" : "=v"(r) : "v"(lo), "v"(hi));
    return r;
}
#define FMIX_LO(a, w, u) \
    asm("v_fma_mix_f32 %0, %1, %2, %0 op_sel_hi:[0,1,0]" : "+v"(a) : "v"(w), "v"(u))
#define FMIX_HI(a, w, u) \
    asm("v_fma_mix_f32 %0, %1, %2, %0 op_sel:[0,1,0] op_sel_hi:[0,1,0]" : "+v"(a) : "v"(w), "v"(u))
#define KEEP(x) asm volatile("" :: "v"(x))

// ---------- workspace layout ----------
#define ROWPTR_OFF 0
#define COLW_OFF   4352
#define SELFW_OFF  (4352 + 73728)
#define PERM_OFF   (SELFW_OFF + 4096)
#define W2T_OFF    (PERM_OFF + 4096)

// ---------- LDS layout ----------
#define TSTR_B 144
#define SM_TILE_BYTES (N_ATOMS * TSTR_B)      // 147456
#define SM_CT_OFF SM_TILE_BYTES               // ctile4: 16384 B
#define SM_TOTAL (SM_TILE_BYTES + 16384)      // 163840

// =====================================================================
// Kernel 1: CSR + norm weights + degree-sorted perm + W2^T f16.
// =====================================================================
__global__ __launch_bounds__(1024) void build_csr(
    const int* __restrict__ ei,
    int*  __restrict__ rowptr,
    int2* __restrict__ colw,
    float* __restrict__ selfw_g,
    int*  __restrict__ perm_g,
    u32*  __restrict__ w2t,
    const float* __restrict__ W2)
{
    __shared__ int   sdeg[N_ATOMS];
    __shared__ int   sstart[N_ATOMS];
    __shared__ float sdinv[N_ATOMS];
    __shared__ int   wtot[16];
    __shared__ int   hist[128];
    const int t = threadIdx.x;
    const int lane = t & 63;
    const int w = t >> 6;
    const int* srcA = ei;
    const int* dstA = ei + N_EDGES;

    sdeg[t] = 0;
    if (t < 128) hist[t] = 0;
    __syncthreads();
    for (int e = t; e < N_EDGES; e += 1024) atomicAdd(&sdeg[dstA[e]], 1);
    __syncthreads();

    const int deg  = sdeg[t];
    const int pdeg = (deg + 1) & ~1;
    int v = pdeg;
    #pragma unroll
    for (int d = 1; d < 64; d <<= 1) {
        int u = __shfl_up(v, d, 64);
        if (lane >= d) v += u;
    }
    if (lane == 63) wtot[w] = v;
    __syncthreads();
    if (t == 0) {
        int run = 0;
        #pragma unroll
        for (int i = 0; i < 16; ++i) { int c = wtot[i]; wtot[i] = run; run += c; }
    }
    __syncthreads();
    const int start = v - pdeg + wtot[w];
    sstart[t] = start;
    const float dv = rsqrtf((float)deg + 1.0f);
    sdinv[t] = dv;
    rowptr[t] = start;
    if (t == N_ATOMS - 1) rowptr[N_ATOMS] = start + pdeg;
    selfw_g[t] = dv * dv;
    if (deg & 1) colw[start + deg] = make_int2(0, 0);

    #pragma unroll
    for (int i = 0; i < 2; ++i) {
        const int idx = t + i * 1024;
        const int c = idx >> 5, kk = idx & 31;
        w2t[c * 32 + kk] = pkrtz(W2[(2 * kk) * 64 + c], W2[(2 * kk + 1) * 64 + c]);
    }

    const int dcl = deg < 127 ? deg : 127;
    atomicAdd(&hist[dcl], 1);
    sdeg[t] = 0;
    __syncthreads();
    if (t == 0) {
        int run = 0;
        for (int i = 0; i < 128; ++i) { int c = hist[i]; hist[i] = run; run += c; }
    }
    __syncthreads();
    const int pos = atomicAdd(&hist[dcl], 1);
    perm_g[pos] = t;
    __syncthreads();

    for (int e = t; e < N_EDGES; e += 1024) {
        const int d = dstA[e];
        const int s = srcA[e];
        const int slot = atomicAdd(&sdeg[d], 1);
        const float wgt = sdinv[s] * sdinv[d];
        colw[sstart[d] + slot] = make_int2(s, __float_as_int(wgt));
    }
}

// =====================================================================
// Kernel 2 (templated): MODE 3 = real fused kernel (R5 structure).
// MODE 1 = phases 0-1 only x REPS; MODE 2 = phases 0-2 x REPS.
// Ablation dispatches appear separately in rocprof.
// =====================================================================
template<int MODE, int REPS>
__global__ __launch_bounds__(1024, 4) void gnn_main(
    const float* __restrict__ x,
    const int*  __restrict__ rowptr,
    const int2* __restrict__ colw,
    const float* __restrict__ selfw_g,
    const int*  __restrict__ perm_g,
    const float* __restrict__ W1, const float* __restrict__ b1,
    const u32*  __restrict__ w2t, const float* __restrict__ b2,
    const float* __restrict__ Wp, const float* __restrict__ bp,
    float* __restrict__ out)
{
    extern __shared__ char smem[];
    float4* ctile4 = (float4*)(smem + SM_CT_OFF);
    float*  paux   = (float*)ctile4;
    float*  wpool  = paux;
    float*  gvec   = paux + 1024;
    float*  proj   = paux + 1088;
    int*    satom  = (int*)(paux + 1600);

    const int t = threadIdx.x;
    const int b = blockIdx.x;
    const float* xb = x + (size_t)b * (3 * N_ATOMS);

    // ---- phase 0: coords -> ctile4 ----
    {
        float4 c;
        c.x = xb[3 * t]; c.y = xb[3 * t + 1]; c.z = xb[3 * t + 2]; c.w = 0.0f;
        ctile4[t] = c;
    }
    __syncthreads();

    // per-thread phase-1 constants
    const int atom1 = perm_g[t];
    const int s0 = rowptr[atom1], s1 = rowptr[atom1 + 1];
    const float sw = selfw_g[atom1];

    // phase-2 constants
    const int w   = t >> 6;
    const int g   = (t & 63) >> 3;
    const int m   = t & 7;
    const int mo  = m * 16;

    int atoms[8], s0a[8], npa[8];
    float swa[8];
    if constexpr (MODE >= 2) {
        #pragma unroll
        for (int k = 0; k < 8; ++k) {
            atoms[k] = perm_g[k * 128 + w * 8 + g];
            const int r0 = rowptr[atoms[k]];
            const int r1 = rowptr[atoms[k] + 1];
            s0a[k] = r0;
            npa[k] = (r1 - r0) >> 1;
            swa[k] = selfw_g[atoms[k]];
        }
    }

    u32 pr[8][4];

    #pragma unroll 1
    for (int rep = 0; rep < REPS; ++rep) {
        // ---- phase 1: aggregate coords, GEMM1 + leaky -> fp16 tile ----
        {
            const float4 cs = ctile4[atom1];
            float A0 = sw * cs.x, A1 = sw * cs.y, A2 = sw * cs.z;
            int4 cur = make_int4(0, 0, 0, 0);
            if (s0 < s1) cur = *(const int4*)(colw + s0);
            for (int j = s0; j < s1; j += 2) {
                const int jn = (j + 2 < s1) ? (j + 2) : s0;
                const int4 nxt = *(const int4*)(colw + jn);
                const float4 c0 = ctile4[cur.x];
                const float4 c1 = ctile4[cur.z];
                const float w0 = __int_as_float(cur.y), w1 = __int_as_float(cur.w);
                A0 += w0 * c0.x + w1 * c1.x;
                A1 += w0 * c0.y + w1 * c1.y;
                A2 += w0 * c0.z + w1 * c1.z;
                cur = nxt;
            }
            u32 pw[32];
            #pragma unroll
            for (int p = 0; p < 32; ++p) {
                f32x2 vv = *(const f32x2*)(b1 + 2 * p);
                vv = __builtin_elementwise_fma((f32x2){A0, A0}, *(const f32x2*)(W1 + 2 * p), vv);
                vv = __builtin_elementwise_fma((f32x2){A1, A1}, *(const f32x2*)(W1 + 64 + 2 * p), vv);
                vv = __builtin_elementwise_fma((f32x2){A2, A2}, *(const f32x2*)(W1 + 128 + 2 * p), vv);
                vv.x = fmaxf(vv.x, NEG * vv.x);
                vv.y = fmaxf(vv.y, NEG * vv.y);
                pw[p] = pkrtz(vv.x, vv.y);
            }
            uint4* trow = (uint4*)(smem + (size_t)atom1 * TSTR_B);
            #pragma unroll
            for (int q = 0; q < 8; ++q)
                trow[q] = make_uint4(pw[4 * q], pw[4 * q + 1], pw[4 * q + 2], pw[4 * q + 3]);
        }
        if constexpr (MODE == 1) continue;

        __syncthreads();

        // ---- phase 2: gather h1; 8 rounds, 8 lanes/atom, chunk mo ----
        #pragma unroll
        for (int k = 0; k < 8; ++k) {
            const int atom = atoms[k];
            float acc[8];
            #pragma unroll
            for (int f = 0; f < 8; ++f) acc[f] = 0.0f;
            {
                const float swk = swa[k];
                const uint4 sv = *(const uint4*)(smem + (size_t)atom * TSTR_B + mo);
                FMIX_LO(acc[0], swk, sv.x); FMIX_HI(acc[1], swk, sv.x);
                FMIX_LO(acc[2], swk, sv.y); FMIX_HI(acc[3], swk, sv.y);
                FMIX_LO(acc[4], swk, sv.z); FMIX_HI(acc[5], swk, sv.z);
                FMIX_LO(acc[6], swk, sv.w); FMIX_HI(acc[7], swk, sv.w);
            }
            for (int j = s0a[k]; j < s0a[k] + 2 * npa[k]; j += 2) {
                const int4 cw = *(const int4*)(colw + j);
                const uint4 qA = *(const uint4*)(smem + (size_t)cw.x * TSTR_B + mo);
                const uint4 qB = *(const uint4*)(smem + (size_t)cw.z * TSTR_B + mo);
                const float wA = __int_as_float(cw.y);
                const float wB = __int_as_float(cw.w);
                FMIX_LO(acc[0], wA, qA.x); FMIX_HI(acc[1], wA, qA.x);
                FMIX_LO(acc[2], wA, qA.y); FMIX_HI(acc[3], wA, qA.y);
                FMIX_LO(acc[4], wA, qA.z); FMIX_HI(acc[5], wA, qA.z);
                FMIX_LO(acc[6], wA, qA.w); FMIX_HI(acc[7], wA, qA.w);
                FMIX_LO(acc[0], wB, qB.x); FMIX_HI(acc[1], wB, qB.x);
                FMIX_LO(acc[2], wB, qB.y); FMIX_HI(acc[3], wB, qB.y);
                FMIX_LO(acc[4], wB, qB.z); FMIX_HI(acc[5], wB, qB.z);
                FMIX_LO(acc[6], wB, qB.w); FMIX_HI(acc[7], wB, qB.w);
            }
            pr[k][0] = pkrtz(acc[0], acc[1]);
            pr[k][1] = pkrtz(acc[2], acc[3]);
            pr[k][2] = pkrtz(acc[4], acc[5]);
            pr[k][3] = pkrtz(acc[6], acc[7]);
        }

        if constexpr (MODE == 2) {
            #pragma unroll
            for (int k = 0; k < 8; ++k) {
                KEEP(pr[k][0]); KEEP(pr[k][1]); KEEP(pr[k][2]); KEEP(pr[k][3]);
            }
            __syncthreads();
            continue;
        }
    }

    if constexpr (MODE == 1) {
        __syncthreads();
        if (t == 0) {
            u32 v = *(volatile u32*)smem;
            KEEP(v);
        }
        return;
    }
    if constexpr (MODE == 2) return;

    if constexpr (MODE == 3) {
        __syncthreads();   // ALL gathers done -> safe to overwrite tile

        #pragma unroll
        for (int k = 0; k < 8; ++k) {
            *(uint4*)(smem + (size_t)atoms[k] * TSTR_B + mo) =
                make_uint4(pr[k][0], pr[k][1], pr[k][2], pr[k][3]);
        }
        if (m == 0) {
            #pragma unroll
            for (int k = 0; k < 8; ++k) satom[w * 64 + k * 8 + g] = atoms[k];
        }
        __syncthreads();

        // ---- phase 3: GEMM2 via MFMA f16 + bias + leaky + pool ----
        {
            const int l15 = t & 15;
            const int lq  = (t & 63) >> 4;

            f16x8 wf[2][4];
            #pragma unroll
            for (int kt = 0; kt < 2; ++kt)
                #pragma unroll
                for (int ct = 0; ct < 4; ++ct)
                    wf[kt][ct] = *(const f16x8*)(w2t + (ct * 16 + l15) * 32 + kt * 16 + lq * 4);
            float bias[4];
            #pragma unroll
            for (int ct = 0; ct < 4; ++ct) bias[ct] = b2[ct * 16 + l15];

            float pool[4] = {0.f, 0.f, 0.f, 0.f};
            #pragma unroll
            for (int rt = 0; rt < 4; ++rt) {
                const int arow = satom[w * 64 + rt * 16 + l15];
                const char* ab = smem + (size_t)arow * TSTR_B + lq * 16;
                const f16x8 a0 = *(const f16x8*)(ab);
                const f16x8 a1 = *(const f16x8*)(ab + 64);
                #pragma unroll
                for (int ct = 0; ct < 4; ++ct) {
                    f32x4 cf = {0.f, 0.f, 0.f, 0.f};
                    cf = __builtin_amdgcn_mfma_f32_16x16x32_f16(a0, wf[0][ct], cf, 0, 0, 0);
                    cf = __builtin_amdgcn_mfma_f32_16x16x32_f16(a1, wf[1][ct], cf, 0, 0, 0);
                    float s = 0.0f;
                    #pragma unroll
                    for (int r = 0; r < 4; ++r) {
                        const float vv = cf[r] + bias[ct];
                        s += fmaxf(vv, NEG * vv);
                    }
                    pool[ct] += s;
                }
            }
            #pragma unroll
            for (int ct = 0; ct < 4; ++ct) {
                pool[ct] += __shfl_xor(pool[ct], 16, 64);
                pool[ct] += __shfl_xor(pool[ct], 32, 64);
            }
            if ((t & 63) < 16) {
                #pragma unroll
                for (int ct = 0; ct < 4; ++ct)
                    wpool[w * 64 + ct * 16 + l15] = pool[ct];
            }
        }
        __syncthreads();

        if (t < 64) {
            float s = 0.0f;
            #pragma unroll
            for (int ww = 0; ww < 16; ++ww) s += wpool[ww * 64 + t];
            gvec[t] = s * (1.0f / 1024.0f);
        }
        __syncthreads();
        if (t < 512) {
            const int col = t & 127, pc = t >> 7;
            float s = 0.0f;
            #pragma unroll
            for (int f = 0; f < 16; ++f)
                s += gvec[pc * 16 + f] * Wp[(pc * 16 + f) * 128 + col];
            proj[pc * 128 + col] = s;
        }
        __syncthreads();
        if (t < 128) {
            float s = bp[t] + proj[t] + proj[128 + t] + proj[256 + t] + proj[384 + t];
            s = fmaxf(s, NEG * s);
            out[(size_t)b * 128 + t] = s;
        }
    }
}

// =====================================================================
extern "C" void kernel_launch(void* const* d_in, const int* in_sizes, int n_in,
                              void* d_out, int out_size, void* d_ws, size_t ws_size,
                              hipStream_t stream) {
    const float* x  = (const float*)d_in[0];
    const int*   ei = (const int*)  d_in[1];
    const float* W1 = (const float*)d_in[2];
    const float* b1 = (const float*)d_in[3];
    const float* W2 = (const float*)d_in[4];
    const float* b2 = (const float*)d_in[5];
    const float* Wp = (const float*)d_in[6];
    const float* bp = (const float*)d_in[7];
    float* out = (float*)d_out;

    char* ws = (char*)d_ws;
    int*   rowptr = (int*)  (ws + ROWPTR_OFF);
    int2*  colw   = (int2*) (ws + COLW_OFF);
    float* selfw  = (float*)(ws + SELFW_OFF);
    int*   perm   = (int*)  (ws + PERM_OFF);
    u32*   w2t    = (u32*)  (ws + W2T_OFF);

    build_csr<<<1, 1024, 0, stream>>>(ei, rowptr, colw, selfw, perm, w2t, W2);

    (void)hipFuncSetAttribute((const void*)gnn_main<3, 1>,
                              hipFuncAttributeMaxDynamicSharedMemorySize, SM_TOTAL);
    (void)hipFuncSetAttribute((const void*)gnn_main<2, 3>,
                              hipFuncAttributeMaxDynamicSharedMemorySize, SM_TOTAL);
    (void)hipFuncSetAttribute((const void*)gnn_main<1, 16>,
                              hipFuncAttributeMaxDynamicSharedMemorySize, SM_TOTAL);

    // real kernel (produces d_out)
    gnn_main<3, 1><<<NBATCH, 1024, SM_TOTAL, stream>>>(
        x, rowptr, colw, selfw, perm, W1, b1, w2t, b2, Wp, bp, out);
    // ablation probes (no global writes; appear as separate rocprof dispatches)
    gnn_main<2, 3><<<NBATCH, 1024, SM_TOTAL, stream>>>(
        x, rowptr, colw, selfw, perm, W1, b1, w2t, b2, Wp, bp, out);
    gnn_main<1, 16><<<NBATCH, 1024, SM_TOTAL, stream>>>(
        x, rowptr, colw, selfw, perm, W1, b1, w2t, b2, Wp, bp, out);
}

// Round 10
// 43.129 us; speedup vs baseline: 3.5043x; 3.5043x over previous
//
#include <hip/hip_runtime.h>

#define N_ATOMS 1024
#define N_EDGES 8192
#define EPAD    (N_EDGES + N_ATOMS)
#define NBATCH  256
#define NEG     0.01f

typedef unsigned int u32;
typedef __attribute__((ext_vector_type(2))) float f32x2;
typedef __attribute__((ext_vector_type(4))) float f32x4;
typedef __attribute__((ext_vector_type(8))) _Float16 f16x8;

__device__ __forceinline__ u32 pkrtz(float lo, float hi) {
    u32 r;
    asm("v_cvt_pkrtz_f16_f32 %0, %1, %2" : "=v"(r) : "v"(lo), "v"(hi));
    return r;
}
#define FMIX_LO(a, w, u) \
    asm("v_fma_mix_f32 %0, %1, %2, %0 op_sel_hi:[0,1,0]" : "+v"(a) : "v"(w), "v"(u))
#define FMIX_HI(a, w, u) \
    asm("v_fma_mix_f32 %0, %1, %2, %0 op_sel:[0,1,0] op_sel_hi:[0,1,0]" : "+v"(a) : "v"(w), "v"(u))

// ---------- workspace layout (all slot-ordered) ----------
#define META_OFF   0                      // int2[1024] {colw_start, npairs}
#define COLW_OFF   8192                   // int2[EPAD] {src_slot, w_bits}
#define SELFW_OFF  (8192 + 73728)         // float[1024]
#define IPERM_OFF  (SELFW_OFF + 4096)     // int[1024] atom -> slot
#define W2T_OFF    (IPERM_OFF + 4096)     // u32[2048] f16-pair W2^T

// ---------- LDS layout ----------
#define TSTR_B 144                            // tile row stride bytes
#define SM_TILE_BYTES (N_ATOMS * TSTR_B)      // 147456
#define SM_CT_OFF SM_TILE_BYTES               // ctile4: 16384 B
#define SM_TOTAL (SM_TILE_BYTES + 16384)      // 163840 == 160 KiB

// =====================================================================
// Kernel 1: CSR (dst-grouped, even-padded, SRC-SLOT encoded) + slot-
// ordered meta/selfw + iperm + W2^T f16. 1 block, amortized.
// =====================================================================
__global__ __launch_bounds__(1024) void build_csr(
    const int* __restrict__ ei,
    int2* __restrict__ colw,
    int2* __restrict__ meta,
    float* __restrict__ selfw_s,
    int*  __restrict__ iperm_g,
    u32*  __restrict__ w2t,
    const float* __restrict__ W2)
{
    __shared__ int   sdeg[N_ATOMS];
    __shared__ int   sstart[N_ATOMS];
    __shared__ int   siperm[N_ATOMS];
    __shared__ float sdinv[N_ATOMS];
    __shared__ int   wtot[16];
    __shared__ int   hist[128];
    const int t = threadIdx.x;
    const int lane = t & 63;
    const int w = t >> 6;
    const int* srcA = ei;
    const int* dstA = ei + N_EDGES;

    sdeg[t] = 0;
    if (t < 128) hist[t] = 0;
    __syncthreads();
    for (int e = t; e < N_EDGES; e += 1024) atomicAdd(&sdeg[dstA[e]], 1);
    __syncthreads();

    const int deg  = sdeg[t];
    const int pdeg = (deg + 1) & ~1;
    int v = pdeg;
    #pragma unroll
    for (int d = 1; d < 64; d <<= 1) {
        int u = __shfl_up(v, d, 64);
        if (lane >= d) v += u;
    }
    if (lane == 63) wtot[w] = v;
    __syncthreads();
    if (t == 0) {
        int run = 0;
        #pragma unroll
        for (int i = 0; i < 16; ++i) { int c = wtot[i]; wtot[i] = run; run += c; }
    }
    __syncthreads();
    const int start = v - pdeg + wtot[w];   // even (all pdeg even)
    sstart[t] = start;
    const float dv = rsqrtf((float)deg + 1.0f);
    sdinv[t] = dv;
    if (deg & 1) colw[start + deg] = make_int2(0, 0);   // zero pad slot

    // W2^T in f16 pairs
    #pragma unroll
    for (int i = 0; i < 2; ++i) {
        const int idx = t + i * 1024;
        const int c = idx >> 5, kk = idx & 31;
        w2t[c * 32 + kk] = pkrtz(W2[(2 * kk) * 64 + c], W2[(2 * kk + 1) * 64 + c]);
    }

    // degree counting sort -> slot of atom t
    const int dcl = deg < 127 ? deg : 127;
    atomicAdd(&hist[dcl], 1);
    __syncthreads();
    if (t == 0) {
        int run = 0;
        for (int i = 0; i < 128; ++i) { int c = hist[i]; hist[i] = run; run += c; }
    }
    __syncthreads();
    const int pos = atomicAdd(&hist[dcl], 1);   // slot of atom t
    siperm[t] = pos;
    iperm_g[t] = pos;
    meta[pos] = make_int2(start, pdeg >> 1);
    selfw_s[pos] = dv * dv;
    sdeg[t] = 0;   // reuse as fill counters
    __syncthreads();

    for (int e = t; e < N_EDGES; e += 1024) {
        const int d = dstA[e];
        const int s = srcA[e];
        const int slot = atomicAdd(&sdeg[d], 1);
        const float wgt = sdinv[s] * sdinv[d];
        colw[sstart[d] + slot] = make_int2(siperm[s], __float_as_int(wgt));
    }
}

// =====================================================================
// Kernel 2: fused GCN x2 + mean-pool + project. 1 block per molecule.
// Tile rows indexed by SLOT: phase-1 writes, agg writeback, and MFMA
// reads are all LINEAR (conflict-free); only edge gather rows random.
// =====================================================================
__global__ __launch_bounds__(1024, 4) void gnn_main(
    const float* __restrict__ x,
    const int2* __restrict__ meta,
    const int2* __restrict__ colw,
    const float* __restrict__ selfw_s,
    const int*  __restrict__ iperm_g,
    const float* __restrict__ W1, const float* __restrict__ b1,
    const u32*  __restrict__ w2t, const float* __restrict__ b2,
    const float* __restrict__ Wp, const float* __restrict__ bp,
    float* __restrict__ out)
{
    extern __shared__ char smem[];
    float4* ctile4 = (float4*)(smem + SM_CT_OFF);  // [1024] coords by SLOT
    float*  paux   = (float*)ctile4;               // aliased post-phase-1:
    float*  wpool  = paux;                         //   [16][64]
    float*  gvec   = paux + 1024;                  //   [64]
    float*  proj   = paux + 1088;                  //   [4][128]

    const int t = threadIdx.x;
    const int b = blockIdx.x;
    const float* xb = x + (size_t)b * (3 * N_ATOMS);

    // ---- phase 0: coords of atom t -> ctile4[slot(t)] ----
    {
        const int ip = iperm_g[t];
        float4 c;
        c.x = xb[3 * t]; c.y = xb[3 * t + 1]; c.z = xb[3 * t + 2]; c.w = 0.0f;
        ctile4[ip] = c;
    }
    __syncthreads();

    // ---- phase 1 (slot t): aggregate coords, GEMM1 + leaky -> tile row t ----
    {
        const int2 mt = meta[t];
        const int s0 = mt.x, np1 = mt.y;
        const float sw = selfw_s[t];
        const float4 cs = ctile4[t];
        float A0 = sw * cs.x, A1 = sw * cs.y, A2 = sw * cs.z;
        int4 cur = make_int4(0, 0, 0, 0);
        if (np1 > 0) cur = *(const int4*)(colw + s0);
        for (int jj = 0; jj < np1; ++jj) {
            const int4 nxt = (jj + 1 < np1) ? *(const int4*)(colw + s0 + 2 * (jj + 1)) : cur;
            const float4 c0 = ctile4[cur.x];
            const float4 c1 = ctile4[cur.z];
            const float w0 = __int_as_float(cur.y), w1 = __int_as_float(cur.w);
            A0 += w0 * c0.x + w1 * c1.x;
            A1 += w0 * c0.y + w1 * c1.y;
            A2 += w0 * c0.z + w1 * c1.z;
            cur = nxt;
        }
        u32 pw[32];
        #pragma unroll
        for (int p = 0; p < 32; ++p) {
            f32x2 vv = *(const f32x2*)(b1 + 2 * p);
            vv = __builtin_elementwise_fma((f32x2){A0, A0}, *(const f32x2*)(W1 + 2 * p), vv);
            vv = __builtin_elementwise_fma((f32x2){A1, A1}, *(const f32x2*)(W1 + 64 + 2 * p), vv);
            vv = __builtin_elementwise_fma((f32x2){A2, A2}, *(const f32x2*)(W1 + 128 + 2 * p), vv);
            vv.x = fmaxf(vv.x, NEG * vv.x);
            vv.y = fmaxf(vv.y, NEG * vv.y);
            pw[p] = pkrtz(vv.x, vv.y);
        }
        uint4* trow = (uint4*)(smem + (size_t)t * TSTR_B);   // LINEAR write
        #pragma unroll
        for (int q = 0; q < 8; ++q)
            trow[q] = make_uint4(pw[4 * q], pw[4 * q + 1], pw[4 * q + 2], pw[4 * q + 3]);
    }

    // phase-2 setup (global reads only; before the barrier)
    const int w   = t >> 6;
    const int g   = (t & 63) >> 3;
    const int m   = t & 7;
    const int mo  = m * 16;

    int s0a[8], npa[8];
    float swa[8];
    #pragma unroll
    for (int k = 0; k < 8; ++k) {
        const int slot = k * 128 + w * 8 + g;
        const int2 mk = meta[slot];
        s0a[k] = mk.x;
        npa[k] = mk.y;
        swa[k] = selfw_s[slot];
    }
    __syncthreads();

    // ---- phase 2: gather; 8 lanes/slot, chunk mo; slot rows ----
    u32 pr[8][4];
    #pragma unroll
    for (int k = 0; k < 8; ++k) {
        const int slot = k * 128 + w * 8 + g;
        float acc[8];
        #pragma unroll
        for (int f = 0; f < 8; ++f) acc[f] = 0.0f;
        {
            const float swk = swa[k];
            const uint4 sv = *(const uint4*)(smem + (size_t)slot * TSTR_B + mo);
            FMIX_LO(acc[0], swk, sv.x); FMIX_HI(acc[1], swk, sv.x);
            FMIX_LO(acc[2], swk, sv.y); FMIX_HI(acc[3], swk, sv.y);
            FMIX_LO(acc[4], swk, sv.z); FMIX_HI(acc[5], swk, sv.z);
            FMIX_LO(acc[6], swk, sv.w); FMIX_HI(acc[7], swk, sv.w);
        }
        for (int j = s0a[k]; j < s0a[k] + 2 * npa[k]; j += 2) {
            const int4 cw = *(const int4*)(colw + j);
            const uint4 qA = *(const uint4*)(smem + (size_t)cw.x * TSTR_B + mo);
            const uint4 qB = *(const uint4*)(smem + (size_t)cw.z * TSTR_B + mo);
            const float wA = __int_as_float(cw.y);
            const float wB = __int_as_float(cw.w);
            FMIX_LO(acc[0], wA, qA.x); FMIX_HI(acc[1], wA, qA.x);
            FMIX_LO(acc[2], wA, qA.y); FMIX_HI(acc[3], wA, qA.y);
            FMIX_LO(acc[4], wA, qA.z); FMIX_HI(acc[5], wA, qA.z);
            FMIX_LO(acc[6], wA, qA.w); FMIX_HI(acc[7], wA, qA.w);
            FMIX_LO(acc[0], wB, qB.x); FMIX_HI(acc[1], wB, qB.x);
            FMIX_LO(acc[2], wB, qB.y); FMIX_HI(acc[3], wB, qB.y);
            FMIX_LO(acc[4], wB, qB.z); FMIX_HI(acc[5], wB, qB.z);
            FMIX_LO(acc[6], wB, qB.w); FMIX_HI(acc[7], wB, qB.w);
        }
        pr[k][0] = pkrtz(acc[0], acc[1]);
        pr[k][1] = pkrtz(acc[2], acc[3]);
        pr[k][2] = pkrtz(acc[4], acc[5]);
        pr[k][3] = pkrtz(acc[6], acc[7]);
    }

    // epilogue global loads: issue before the barrier (latency hidden)
    const int l15 = t & 15;
    const int lq  = (t & 63) >> 4;
    f16x8 wf[2][4];
    #pragma unroll
    for (int kt = 0; kt < 2; ++kt)
        #pragma unroll
        for (int ct = 0; ct < 4; ++ct)
            wf[kt][ct] = *(const f16x8*)(w2t + (ct * 16 + l15) * 32 + kt * 16 + lq * 4);
    float bias[4];
    #pragma unroll
    for (int ct = 0; ct < 4; ++ct) bias[ct] = b2[ct * 16 + l15];
    // Wp preload for proj (threads 0..511)
    float wpv[16];
    {
        const int col = t & 127, pc = (t >> 7) & 3;
        #pragma unroll
        for (int f = 0; f < 16; ++f)
            wpv[f] = Wp[(pc * 16 + f) * 128 + col];
    }

    __syncthreads();   // ALL gathers done -> safe to overwrite tile

    // writeback agg chunks to own slot rows (LINEAR: rows w*8+g+128k)
    #pragma unroll
    for (int k = 0; k < 8; ++k) {
        const int slot = k * 128 + w * 8 + g;
        *(uint4*)(smem + (size_t)slot * TSTR_B + mo) =
            make_uint4(pr[k][0], pr[k][1], pr[k][2], pr[k][3]);
    }
    __syncthreads();

    // ---- phase 3: GEMM2 via MFMA f16 over LINEAR rows + leaky + pool ----
    {
        float pool[4] = {0.f, 0.f, 0.f, 0.f};
        #pragma unroll
        for (int rt = 0; rt < 4; ++rt) {
            const int row = w * 64 + rt * 16 + l15;    // consecutive rows
            const char* ab = smem + (size_t)row * TSTR_B + lq * 16;
            const f16x8 a0 = *(const f16x8*)(ab);
            const f16x8 a1 = *(const f16x8*)(ab + 64);
            #pragma unroll
            for (int ct = 0; ct < 4; ++ct) {
                f32x4 cf = {0.f, 0.f, 0.f, 0.f};
                cf = __builtin_amdgcn_mfma_f32_16x16x32_f16(a0, wf[0][ct], cf, 0, 0, 0);
                cf = __builtin_amdgcn_mfma_f32_16x16x32_f16(a1, wf[1][ct], cf, 0, 0, 0);
                float s = 0.0f;
                #pragma unroll
                for (int r = 0; r < 4; ++r) {
                    const float vv = cf[r] + bias[ct];
                    s += fmaxf(vv, NEG * vv);
                }
                pool[ct] += s;
            }
        }
        #pragma unroll
        for (int ct = 0; ct < 4; ++ct) {
            pool[ct] += __shfl_xor(pool[ct], 16, 64);
            pool[ct] += __shfl_xor(pool[ct], 32, 64);
        }
        if ((t & 63) < 16) {
            #pragma unroll
            for (int ct = 0; ct < 4; ++ct)
                wpool[w * 64 + ct * 16 + l15] = pool[ct];
        }
    }
    __syncthreads();

    // ---- final pool + project (Wp already in registers) ----
    if (t < 64) {
        float s = 0.0f;
        #pragma unroll
        for (int ww = 0; ww < 16; ++ww) s += wpool[ww * 64 + t];
        gvec[t] = s * (1.0f / 1024.0f);
    }
    __syncthreads();
    if (t < 512) {
        const int col = t & 127, pc = t >> 7;
        float s = 0.0f;
        #pragma unroll
        for (int f = 0; f < 16; ++f)
            s += gvec[pc * 16 + f] * wpv[f];
        proj[pc * 128 + col] = s;
    }
    __syncthreads();
    if (t < 128) {
        float s = bp[t] + proj[t] + proj[128 + t] + proj[256 + t] + proj[384 + t];
        s = fmaxf(s, NEG * s);
        out[(size_t)b * 128 + t] = s;
    }
}

// =====================================================================
extern "C" void kernel_launch(void* const* d_in, const int* in_sizes, int n_in,
                              void* d_out, int out_size, void* d_ws, size_t ws_size,
                              hipStream_t stream) {
    const float* x  = (const float*)d_in[0];
    const int*   ei = (const int*)  d_in[1];
    const float* W1 = (const float*)d_in[2];
    const float* b1 = (const float*)d_in[3];
    const float* W2 = (const float*)d_in[4];
    const float* b2 = (const float*)d_in[5];
    const float* Wp = (const float*)d_in[6];
    const float* bp = (const float*)d_in[7];
    float* out = (float*)d_out;

    char* ws = (char*)d_ws;
    int2*  meta   = (int2*) (ws + META_OFF);
    int2*  colw   = (int2*) (ws + COLW_OFF);
    float* selfw  = (float*)(ws + SELFW_OFF);
    int*   iperm  = (int*)  (ws + IPERM_OFF);
    u32*   w2t    = (u32*)  (ws + W2T_OFF);

    build_csr<<<1, 1024, 0, stream>>>(ei, colw, meta, selfw, iperm, w2t, W2);

    (void)hipFuncSetAttribute((const void*)gnn_main,
                              hipFuncAttributeMaxDynamicSharedMemorySize, SM_TOTAL);
    gnn_main<<<NBATCH, 1024, SM_TOTAL, stream>>>(
        x, meta, colw, selfw, iperm, W1, b1, w2t, b2, Wp, bp, out);
}